// Round 3
// baseline (155.449 us; speedup 1.0000x reference)
//
#include <hip/hip_runtime.h>
#include <math.h>

// NoisyTopkRouter: x[T,2048] @ {Wg,Wn}[8,2048]^T -> logits[T,8] each,
// noisy = noise * softplus(noisy_pre) + gate; top-2 -> softmax -> scatter.
// T = 32768, D = 2048, E = 8, k = 2.
//
// R3: coalescing fix. R2 had lane=token (stride-8KB) x loads -> 64
// transactions per instruction -> request-rate-bound at ~950 GB/s.
// Now: wave owns 4 consecutive tokens, lanes span 256 contiguous d's ->
// every global load (x AND weights) is one contiguous 1 KB wave access.
// Cross-lane dot-product finish via 6-stage shfl_xor butterfly. No LDS.

#define RD 2048
#define RE 8
#define TPW 4                  // tokens per wave
#define CHUNK 256              // d's per chunk (64 lanes * float4)
#define NCHUNK (RD / CHUNK)    // 8

__global__ __launch_bounds__(256) void noisy_topk_router_kernel(
    const float* __restrict__ x,
    const float* __restrict__ Wg,
    const float* __restrict__ bg,
    const float* __restrict__ Wn,
    const float* __restrict__ bn,
    const float* __restrict__ noise,
    float* __restrict__ out_router,
    float* __restrict__ out_experts)
{
    const int wid = threadIdx.x >> 6;            // wave 0..3
    const int l   = threadIdx.x & 63;            // lane
    const int tokBase = (blockIdx.x * 4 + wid) * TPW;  // 16 tokens/block

    float accg[TPW][RE], accn[TPW][RE];
#pragma unroll
    for (int t = 0; t < TPW; ++t)
#pragma unroll
        for (int e = 0; e < RE; ++e) { accg[t][e] = 0.f; accn[t][e] = 0.f; }

    const int lq = l * 4;                        // lane's float4 offset in chunk

#pragma unroll 1
    for (int c = 0; c < NCHUNK; ++c) {
        const int dbase = c * CHUNK + lq;
        // 4 independent, perfectly coalesced 1 KB x loads
        float4 xv[TPW];
#pragma unroll
        for (int t = 0; t < TPW; ++t)
            xv[t] = *reinterpret_cast<const float4*>(
                x + (size_t)(tokBase + t) * RD + dbase);

#pragma unroll
        for (int e = 0; e < RE; ++e) {
            const float4 wg = *reinterpret_cast<const float4*>(Wg + e * RD + dbase);
            const float4 wn = *reinterpret_cast<const float4*>(Wn + e * RD + dbase);
#pragma unroll
            for (int t = 0; t < TPW; ++t) {
                accg[t][e] = fmaf(xv[t].x, wg.x, accg[t][e]);
                accg[t][e] = fmaf(xv[t].y, wg.y, accg[t][e]);
                accg[t][e] = fmaf(xv[t].z, wg.z, accg[t][e]);
                accg[t][e] = fmaf(xv[t].w, wg.w, accg[t][e]);
                accn[t][e] = fmaf(xv[t].x, wn.x, accn[t][e]);
                accn[t][e] = fmaf(xv[t].y, wn.y, accn[t][e]);
                accn[t][e] = fmaf(xv[t].z, wn.z, accn[t][e]);
                accn[t][e] = fmaf(xv[t].w, wn.w, accn[t][e]);
            }
        }
    }

    // Butterfly reduction across the 64 lanes; afterwards every lane holds
    // the full dot products (fixed order -> deterministic).
#pragma unroll
    for (int m = 1; m < 64; m <<= 1) {
#pragma unroll
        for (int t = 0; t < TPW; ++t)
#pragma unroll
            for (int e = 0; e < RE; ++e) {
                accg[t][e] += __shfl_xor(accg[t][e], m, 64);
                accn[t][e] += __shfl_xor(accn[t][e], m, 64);
            }
    }

    // Epilogue: lane t (0..3) handles token tokBase+t. Branch-free select
    // (compile-time indices only -> no scratch).
    const int tsel = l & 3;
    const int tok  = tokBase + tsel;

    float vg[RE], vn[RE];
#pragma unroll
    for (int e = 0; e < RE; ++e) {
        float a = accg[0][e];
        a = (tsel == 1) ? accg[1][e] : a;
        a = (tsel == 2) ? accg[2][e] : a;
        a = (tsel == 3) ? accg[3][e] : a;
        vg[e] = a + bg[e];
        float b = accn[0][e];
        b = (tsel == 1) ? accn[1][e] : b;
        b = (tsel == 2) ? accn[2][e] : b;
        b = (tsel == 3) ? accn[3][e] : b;
        vn[e] = b + bn[e];
    }

    const float4* nzp = reinterpret_cast<const float4*>(noise + (size_t)tok * RE);
    const float4 nz0 = nzp[0];
    const float4 nz1 = nzp[1];
    const float nzv[RE] = {nz0.x, nz0.y, nz0.z, nz0.w,
                           nz1.x, nz1.y, nz1.z, nz1.w};

    float v[RE];
#pragma unroll
    for (int e = 0; e < RE; ++e) {
        const float p = vn[e];
        // stable softplus: max(p,0) + log1p(exp(-|p|))
        const float sp = fmaxf(p, 0.f) + log1pf(expf(-fabsf(p)));
        v[e] = fmaf(nzv[e], sp, vg[e]);
    }

    // top-2 of 8; strict '>' keeps the lowest index on ties, matching
    // jax.lax.top_k / torch.topk ordering.
    int i1 = 0; float m1 = v[0];
#pragma unroll
    for (int e = 1; e < RE; ++e)
        if (v[e] > m1) { m1 = v[e]; i1 = e; }
    int i2 = -1; float m2 = -INFINITY;
#pragma unroll
    for (int e = 0; e < RE; ++e)
        if (e != i1 && v[e] > m2) { m2 = v[e]; i2 = e; }

    const float e2 = expf(m2 - m1);
    const float inv = 1.f / (1.f + e2);
    const float p1 = inv;
    const float p2 = e2 * inv;

    float r[RE];
#pragma unroll
    for (int e = 0; e < RE; ++e)
        r[e] = (e == i1) ? p1 : ((e == i2) ? p2 : 0.f);

    if (l < TPW) {
        float4* orow = reinterpret_cast<float4*>(out_router + (size_t)tok * RE);
        orow[0] = make_float4(r[0], r[1], r[2], r[3]);
        orow[1] = make_float4(r[4], r[5], r[6], r[7]);
        float2* erow = reinterpret_cast<float2*>(out_experts + (size_t)tok * 2);
        *erow = make_float2((float)i1, (float)i2);
    }
}

extern "C" void kernel_launch(void* const* d_in, const int* in_sizes, int n_in,
                              void* d_out, int out_size, void* d_ws, size_t ws_size,
                              hipStream_t stream) {
    const float* x   = (const float*)d_in[0];
    const float* Wg  = (const float*)d_in[1];
    const float* bg  = (const float*)d_in[2];
    const float* Wn  = (const float*)d_in[3];
    const float* bn  = (const float*)d_in[4];
    const float* nz  = (const float*)d_in[5];
    const int T = in_sizes[0] / RD;              // 32768

    float* out_router  = (float*)d_out;                // T*8 floats
    float* out_experts = out_router + (size_t)T * RE;  // T*2 floats (as f32)

    const int blocks = T / 16;                   // 2048 (16 tokens per block)
    hipLaunchKernelGGL(noisy_topk_router_kernel, dim3(blocks), dim3(256), 0,
                       stream, x, Wg, bg, Wn, bn, nz, out_router, out_experts);
}